// Round 1
// baseline (655.365 us; speedup 1.0000x reference)
//
#include <hip/hip_runtime.h>

// AdaptiveStdPooling2d: x [B=16, C=128, H=512, W=128] fp32
// H_OUT=8, W_OUT=16  ->  kh = 64 (variance axis), kw = 8 (std-sum axis)
// out[b,c,ho,wo] = sum_{j<8} sqrt( var_{r<64}( x[b,c,ho*64+r, wo*8+j] ) + 1e-14 )
//
// Slab (b,c,ho) = 64 rows x 128 cols = contiguous 32 KiB of x.
// One wave per slab; 4 waves per 256-thread block -> 4096 blocks.
// Lane layout: cg = lane&31 owns columns 4cg..4cg+3 (float4),
//              rh = lane>>5 owns rows {2k + rh}, k=0..31  -> each wave load
//              instruction covers rows {2k,2k+1} = ONE contiguous 1-KiB segment
//              (ideal 16 B/lane x 64-lane coalescing unit).
//
// R1 change vs previous best: drop __builtin_nontemporal_load -> plain cached
// vector loads. Rationale: iteration = {2GiB harness fill (~335us, 6.4TB/s)} +
// {kernel (~299us inferred)}; kernel runs at only ~1.8TB/s despite perfect
// coalescing. The nt (no-allocate L2/MALL) bit on a pure-read stream is the
// prime suspect for the 3.5x gap to the BW the fill itself demonstrates.

#define KH 64
#define WIDTH 128
#define W_OUT 16
#define SLABS 16384   // B*C*H_OUT = 16*128*8

typedef float f32x4 __attribute__((ext_vector_type(4)));

__global__ __launch_bounds__(256) void adaptive_std_pool_kernel(
    const float* __restrict__ x, float* __restrict__ out) {
    const int wave = threadIdx.x >> 6;       // 0..3
    const int lane = threadIdx.x & 63;
    const int slab = blockIdx.x * 4 + wave;  // [0, 16384)

    const int cg = lane & 31;                // column group: cols 4cg..4cg+3
    const int rh = lane >> 5;                // row parity: rows 2k+rh

    const f32x4* p = (const f32x4*)(x + (size_t)slab * KH * WIDTH)
                     + (size_t)rh * (WIDTH / 4) + cg;

    f32x4 s  = {0.f, 0.f, 0.f, 0.f};
    f32x4 ss = {0.f, 0.f, 0.f, 0.f};
#pragma unroll
    for (int k = 0; k < 32; ++k) {
        // rows {2k, 2k+1}: stride 2 rows = 64 float4 = 1 KiB
        f32x4 v = p[(size_t)k * (2 * WIDTH / 4)];
        s += v;
        ss += v * v;   // -ffp-contract fuses into v_fmac
    }

    // Combine the two row-parity halves (lane ^ 32, stays in the 64-lane wave).
    s.x  += __shfl_xor(s.x, 32);  s.y  += __shfl_xor(s.y, 32);
    s.z  += __shfl_xor(s.z, 32);  s.w  += __shfl_xor(s.w, 32);
    ss.x += __shfl_xor(ss.x, 32); ss.y += __shfl_xor(ss.y, 32);
    ss.z += __shfl_xor(ss.z, 32); ss.w += __shfl_xor(ss.w, 32);

    const float inv = 1.0f / (float)KH;
    float partial = 0.f;
    {
        float m = s.x * inv;
        partial += sqrtf(fmaxf(ss.x * inv - m * m, 0.f) + 1e-14f);
    }
    {
        float m = s.y * inv;
        partial += sqrtf(fmaxf(ss.y * inv - m * m, 0.f) + 1e-14f);
    }
    {
        float m = s.z * inv;
        partial += sqrtf(fmaxf(ss.z * inv - m * m, 0.f) + 1e-14f);
    }
    {
        float m = s.w * inv;
        partial += sqrtf(fmaxf(ss.w * inv - m * m, 0.f) + 1e-14f);
    }

    // kw=8 bin = columns {8m..8m+7} = lanes {2m, 2m+1} (aligned pair).
    partial += __shfl_xor(partial, 1);

    if (rh == 0 && (lane & 1) == 0) {
        out[slab * W_OUT + (cg >> 1)] = partial;
    }
}

extern "C" void kernel_launch(void* const* d_in, const int* in_sizes, int n_in,
                              void* d_out, int out_size, void* d_ws, size_t ws_size,
                              hipStream_t stream) {
    const float* x = (const float*)d_in[0];
    float* out = (float*)d_out;
    adaptive_std_pool_kernel<<<SLABS / 4, 256, 0, stream>>>(x, out);
}

// Round 2
// 646.938 us; speedup vs baseline: 1.0130x; 1.0130x over previous
//
#include <hip/hip_runtime.h>

// AdaptiveStdPooling2d: x [B=16, C=128, H=512, W=128] fp32
// H_OUT=8, W_OUT=16  ->  kh = 64 (variance axis), kw = 8 (std-sum axis)
// out[b,c,ho,wo] = sum_{j<8} sqrt( var_{r<64}( x[b,c,ho*64+r, wo*8+j] ) + 1e-14 )
//
// Slab (b,c,ho) = 64 rows x 128 cols = contiguous 32 KiB of x.
// One wave per slab; 4 waves per 256-thread block -> 4096 blocks.
// Lane layout: cg = lane&31 owns columns 4cg..4cg+3 (float4),
//              rh = lane>>5 owns rows {2k + rh}  -> each wave load instruction
//              covers rows {2k,2k+1} = ONE contiguous 1-KiB segment.
//
// R2 change: fix latency-bound MLP starvation.
//   Old: full 32x unroll -> ~128 VGPR of load dests + per-load address pairs
//        (offsets >4095 don't fit the 13-bit imm) -> VGPR>256 -> 1 wave/SIMD,
//        near-serial load/consume  => measured ~1.75 TB/s (~2.6 KiB in flight
//        per CU vs 9.4 KiB needed for 6.4 TB/s).
//   New: #pragma unroll 4 (dests = 16 VGPR; offsets {0,1024,2048,3072} all fit
//        the immediate -> 1 address add per 4 loads) + __launch_bounds__(256,4)
//        -> ~50 VGPR, 4 waves/SIMD (16 waves/CU), ~30-48 KiB/CU in flight.
// Keep nontemporal loads (R1 A/B: cached was no better; stream is read-once).

#define KH 64
#define WIDTH 128
#define W_OUT 16
#define SLABS 16384   // B*C*H_OUT = 16*128*8

typedef float f32x4 __attribute__((ext_vector_type(4)));

__global__ __launch_bounds__(256, 4) void adaptive_std_pool_kernel(
    const float* __restrict__ x, float* __restrict__ out) {
    const int wave = threadIdx.x >> 6;       // 0..3
    const int lane = threadIdx.x & 63;
    const int slab = blockIdx.x * 4 + wave;  // [0, 16384)

    const int cg = lane & 31;                // column group: cols 4cg..4cg+3
    const int rh = lane >> 5;                // row parity: rows 2k+rh

    const f32x4* p = (const f32x4*)(x + (size_t)slab * KH * WIDTH)
                     + (size_t)rh * (WIDTH / 4) + cg;

    f32x4 s  = {0.f, 0.f, 0.f, 0.f};
    f32x4 ss = {0.f, 0.f, 0.f, 0.f};
#pragma unroll 4
    for (int k = 0; k < 32; ++k) {
        // rows {2k, 2k+1}: stride 2 rows = 64 float4 = 1 KiB
        f32x4 v = __builtin_nontemporal_load(p + (size_t)k * (2 * WIDTH / 4));
        s += v;
        ss += v * v;   // -ffp-contract fuses into v_fmac
    }

    // Combine the two row-parity halves (lane ^ 32, stays in the 64-lane wave).
    s.x  += __shfl_xor(s.x, 32);  s.y  += __shfl_xor(s.y, 32);
    s.z  += __shfl_xor(s.z, 32);  s.w  += __shfl_xor(s.w, 32);
    ss.x += __shfl_xor(ss.x, 32); ss.y += __shfl_xor(ss.y, 32);
    ss.z += __shfl_xor(ss.z, 32); ss.w += __shfl_xor(ss.w, 32);

    const float inv = 1.0f / (float)KH;
    float partial = 0.f;
    {
        float m = s.x * inv;
        partial += sqrtf(fmaxf(ss.x * inv - m * m, 0.f) + 1e-14f);
    }
    {
        float m = s.y * inv;
        partial += sqrtf(fmaxf(ss.y * inv - m * m, 0.f) + 1e-14f);
    }
    {
        float m = s.z * inv;
        partial += sqrtf(fmaxf(ss.z * inv - m * m, 0.f) + 1e-14f);
    }
    {
        float m = s.w * inv;
        partial += sqrtf(fmaxf(ss.w * inv - m * m, 0.f) + 1e-14f);
    }

    // kw=8 bin = columns {8m..8m+7} = lanes {2m, 2m+1} (aligned pair).
    partial += __shfl_xor(partial, 1);

    if (rh == 0 && (lane & 1) == 0) {
        out[slab * W_OUT + (cg >> 1)] = partial;
    }
}

extern "C" void kernel_launch(void* const* d_in, const int* in_sizes, int n_in,
                              void* d_out, int out_size, void* d_ws, size_t ws_size,
                              hipStream_t stream) {
    const float* x = (const float*)d_in[0];
    float* out = (float*)d_out;
    adaptive_std_pool_kernel<<<SLABS / 4, 256, 0, stream>>>(x, out);
}